// Round 8
// baseline (187.967 us; speedup 1.0000x reference)
//
#include <hip/hip_runtime.h>
#include <math.h>

#ifndef INFINITY
#define INFINITY __builtin_huge_valf()
#endif

static inline int cdiv(int a, int b){ return (a + b - 1) / b; }

typedef __attribute__((ext_vector_type(8))) short bf16x8;
typedef __attribute__((ext_vector_type(4))) float f32x4;

static __device__ __forceinline__ short f2bf(float f){
  unsigned u = __float_as_uint(f);
  unsigned r = (u + 0x7fffu + ((u >> 16) & 1u)) >> 16;
  return (short)r;
}
static __device__ __forceinline__ unsigned pk2bf(float lo, float hi){
  return ((unsigned)(unsigned short)f2bf(hi) << 16) | (unsigned short)(unsigned)f2bf(lo);
}
static __device__ __forceinline__ float bflo(unsigned pair){
  return __uint_as_float((pair & 0xffffu) << 16);
}
static __device__ __forceinline__ float bfhi(unsigned pair){
  return __uint_as_float(pair & 0xffff0000u);
}

// ---------------- utility ----------------

__global__ void zero_i32_k(int* __restrict__ p, int n){
  int i = blockIdx.x * blockDim.x + threadIdx.x;
  if (i < n) p[i] = 0;
}

// fused weight prep: 4 transposes (blocks 0..511) + 4 combined attention vectors (blocks 512..514)
__global__ __launch_bounds__(256) void prepc_k(
    const float* __restrict__ Ws1, short* __restrict__ T1,
    const float* __restrict__ Wl1, short* __restrict__ T2,
    const float* __restrict__ Ws2, short* __restrict__ T3,
    const float* __restrict__ Wl2, short* __restrict__ T4,
    const float* __restrict__ as1, const float* __restrict__ Wd1, const float* __restrict__ ad1,
    const float* __restrict__ as2, const float* __restrict__ Wd2, const float* __restrict__ ad2,
    float* __restrict__ wa_s1, float* __restrict__ wa_d1,
    float* __restrict__ wa_s2, float* __restrict__ wa_d2){
  int g = blockIdx.x;
  if (g < 512){
    const float* W; short* T; int K; int c;
    if (g < 128){ W = Ws1; T = T1; K = 256; c = g; }
    else if (g < 256){ W = Wl1; T = T2; K = 256; c = g - 128; }
    else if (g < 384){ W = Ws2; T = T3; K = 128; c = g - 256; }
    else { W = Wl2; T = T4; K = 128; c = g - 384; }
    for (int k = threadIdx.x; k < K; k += blockDim.x)
      T[(size_t)c * K + k] = f2bf(W[(size_t)k * 128 + c]);
  } else {
    int t = (g - 512) * 256 + threadIdx.x;
    const float* row; const float* a; float* out; int idx;
    if (t < 256){ row = Ws1 + (size_t)t * 128;          a = as1; out = wa_s1; idx = t; }
    else if (t < 512){ row = Wd1 + (size_t)(t-256)*128; a = ad1; out = wa_d1; idx = t-256; }
    else if (t < 640){ row = Ws2 + (size_t)(t-512)*128; a = as2; out = wa_s2; idx = t-512; }
    else { row = Wd2 + (size_t)(t-640)*128;             a = ad2; out = wa_d2; idx = t-640; }
    float s = 0.f;
    #pragma unroll 8
    for (int j = 0; j < 128; ++j) s += row[j] * a[j];
    out[idx] = s;
  }
}

// ---------------- CSR build ----------------

__global__ void deg_count_k(const int* __restrict__ dst, int E, int* __restrict__ deg){
  int e = blockIdx.x * blockDim.x + threadIdx.x;
  if (e < E) atomicAdd(&deg[dst[e]], 1);
}

__global__ __launch_bounds__(1024) void scan1_k(const int* __restrict__ deg, int N,
    int* __restrict__ rowptr, int* __restrict__ bsum){
  __shared__ int buf[1024];
  int t = threadIdx.x;
  int i = blockIdx.x * 1024 + t;
  int v = (i < N) ? deg[i] : 0;
  buf[t] = v;
  __syncthreads();
  #pragma unroll
  for (int o = 1; o < 1024; o <<= 1){
    int add = (t >= o) ? buf[t - o] : 0;
    __syncthreads();
    buf[t] += add;
    __syncthreads();
  }
  if (i < N) rowptr[i] = buf[t] - v;
  if (t == 1023) bsum[blockIdx.x] = buf[1023];
}

__global__ __launch_bounds__(1024) void scan2_k(int* __restrict__ bsum, int nb,
    int* __restrict__ total_out){
  __shared__ int buf[1024];
  int t = threadIdx.x;
  int v = (t < nb) ? bsum[t] : 0;
  buf[t] = v;
  __syncthreads();
  #pragma unroll
  for (int o = 1; o < 1024; o <<= 1){
    int add = (t >= o) ? buf[t - o] : 0;
    __syncthreads();
    buf[t] += add;
    __syncthreads();
  }
  if (t < nb) bsum[t] = buf[t] - v;
  if (t == 1023) *total_out = buf[1023];
}

__global__ __launch_bounds__(1024) void scan3_k(int* __restrict__ rowptr, int* __restrict__ cursor,
    const int* __restrict__ boff, int N){
  int i = blockIdx.x * 1024 + threadIdx.x;
  if (i < N){
    int r = rowptr[i] + boff[blockIdx.x];
    rowptr[i] = r;
    cursor[i] = r;
  }
}

__global__ void scatter_k(const int* __restrict__ src, const int* __restrict__ dst, int E,
                          int* __restrict__ cursor, int* __restrict__ csr_src){
  int e = blockIdx.x * blockDim.x + threadIdx.x;
  if (e < E){
    int d = dst[e];
    int p = atomicAdd(&cursor[d], 1);
    csr_src[p] = src[e];
  }
}

// ---------------- layer-1 GEMM: fp32 A cast during staging, dual bf16 C, ----------------
// fused attention dots computed from fp32 registers at load time, reg-prefetch pipeline.

__global__ __launch_bounds__(256) void gemm1_k(const float* __restrict__ X,
    const short* __restrict__ BT1, const short* __restrict__ BT2,
    const float* __restrict__ vs, const float* __restrict__ vd,
    short* __restrict__ C1, short* __restrict__ C2,
    float* __restrict__ als, float* __restrict__ ald, int M){
  const int K = 256;
  __shared__ int4 As[512];
  __shared__ int4 Bs1[512];
  __shared__ int4 Bs2[512];
  const int tid = threadIdx.x;
  const int lane = tid & 63, wid = tid >> 6;
  const int wm = wid >> 1, wn = wid & 1;
  const int l15 = lane & 15, lhi = lane >> 4;
  const int row0 = blockIdx.x * 128;
  const int r0 = tid >> 2, slot = tid & 3;
  const int so0 = (slot * 16) ^ ((r0 & 3) << 4);   // (r0+64)&3 == r0&3

  const bool v0 = row0 + r0 < M, v1 = row0 + r0 + 64 < M;
  const float* A0 = X + (size_t)(row0 + r0) * K + slot * 8;
  const float* A1 = A0 + (size_t)64 * K;
  const short* B10 = BT1 + (size_t)r0 * K + slot * 8;
  const short* B11 = BT1 + (size_t)(r0 + 64) * K + slot * 8;
  const short* B20 = BT2 + (size_t)r0 * K + slot * 8;
  const short* B21 = BT2 + (size_t)(r0 + 64) * K + slot * 8;

  f32x4 acc[4][4], acc2[4][4];
  #pragma unroll
  for (int m = 0; m < 4; ++m)
    #pragma unroll
    for (int n = 0; n < 4; ++n){ acc[m][n] = (f32x4)(0.f); acc2[m][n] = (f32x4)(0.f); }
  float dps0 = 0.f, dpd0 = 0.f, dps1 = 0.f, dpd1 = 0.f;

  float4 fa0, fa1, fb0, fb1;   // A rows r0 / r0+64, 8 fp32 each
  int4 rb10, rb11, rb20, rb21;
  float4 vsl, vsh, vdl, vdh;
  const float4 z4 = make_float4(0.f, 0.f, 0.f, 0.f);

#define G1_LOAD(kk) do{ \
    fa0 = v0 ? *(const float4*)(A0 + (kk)) : z4; \
    fa1 = v0 ? *(const float4*)(A0 + (kk) + 4) : z4; \
    fb0 = v1 ? *(const float4*)(A1 + (kk)) : z4; \
    fb1 = v1 ? *(const float4*)(A1 + (kk) + 4) : z4; \
    rb10 = *(const int4*)(B10 + (kk)); rb11 = *(const int4*)(B11 + (kk)); \
    rb20 = *(const int4*)(B20 + (kk)); rb21 = *(const int4*)(B21 + (kk)); \
    vsl = *(const float4*)(vs + (kk) + slot * 8); vsh = *(const float4*)(vs + (kk) + slot * 8 + 4); \
    vdl = *(const float4*)(vd + (kk) + slot * 8); vdh = *(const float4*)(vd + (kk) + slot * 8 + 4); \
  }while(0)

  G1_LOAD(0);
  for (int kk = 0; kk < K; kk += 32){
    // attention-dot partials from fp32 regs (full fp32 accuracy)
    dps0 += fa0.x*vsl.x + fa0.y*vsl.y + fa0.z*vsl.z + fa0.w*vsl.w
          + fa1.x*vsh.x + fa1.y*vsh.y + fa1.z*vsh.z + fa1.w*vsh.w;
    dpd0 += fa0.x*vdl.x + fa0.y*vdl.y + fa0.z*vdl.z + fa0.w*vdl.w
          + fa1.x*vdh.x + fa1.y*vdh.y + fa1.z*vdh.z + fa1.w*vdh.w;
    dps1 += fb0.x*vsl.x + fb0.y*vsl.y + fb0.z*vsl.z + fb0.w*vsl.w
          + fb1.x*vsh.x + fb1.y*vsh.y + fb1.z*vsh.z + fb1.w*vsh.w;
    dpd1 += fb0.x*vdl.x + fb0.y*vdl.y + fb0.z*vdl.z + fb0.w*vdl.w
          + fb1.x*vdh.x + fb1.y*vdh.y + fb1.z*vdh.z + fb1.w*vdh.w;
    int4 av0, av1;
    av0.x = (int)pk2bf(fa0.x, fa0.y); av0.y = (int)pk2bf(fa0.z, fa0.w);
    av0.z = (int)pk2bf(fa1.x, fa1.y); av0.w = (int)pk2bf(fa1.z, fa1.w);
    av1.x = (int)pk2bf(fb0.x, fb0.y); av1.y = (int)pk2bf(fb0.z, fb0.w);
    av1.z = (int)pk2bf(fb1.x, fb1.y); av1.w = (int)pk2bf(fb1.z, fb1.w);
    *(int4*)((char*)As + r0 * 64 + so0) = av0;
    *(int4*)((char*)As + (r0 + 64) * 64 + so0) = av1;
    *(int4*)((char*)Bs1 + r0 * 64 + so0) = rb10;
    *(int4*)((char*)Bs1 + (r0 + 64) * 64 + so0) = rb11;
    *(int4*)((char*)Bs2 + r0 * 64 + so0) = rb20;
    *(int4*)((char*)Bs2 + (r0 + 64) * 64 + so0) = rb21;
    __syncthreads();
    if (kk + 32 < K) G1_LOAD(kk + 32);     // prefetch next tile; latency hides under MFMA
    bf16x8 af[4], bfr[4], bf2[4];
    #pragma unroll
    for (int m = 0; m < 4; ++m){
      int ar = wm * 64 + m * 16 + l15;
      af[m] = *(const bf16x8*)((const char*)As + ar * 64 + ((lhi * 16) ^ ((ar & 3) << 4)));
    }
    #pragma unroll
    for (int n = 0; n < 4; ++n){
      int bc = wn * 64 + n * 16 + l15;
      int so = (lhi * 16) ^ ((bc & 3) << 4);
      bfr[n] = *(const bf16x8*)((const char*)Bs1 + bc * 64 + so);
      bf2[n] = *(const bf16x8*)((const char*)Bs2 + bc * 64 + so);
    }
    #pragma unroll
    for (int m = 0; m < 4; ++m)
      #pragma unroll
      for (int n = 0; n < 4; ++n){
        acc[m][n]  = __builtin_amdgcn_mfma_f32_16x16x32_bf16(af[m], bfr[n], acc[m][n], 0, 0, 0);
        acc2[m][n] = __builtin_amdgcn_mfma_f32_16x16x32_bf16(af[m], bf2[n], acc2[m][n], 0, 0, 0);
      }
    __syncthreads();
  }
#undef G1_LOAD
  #pragma unroll
  for (int m = 0; m < 4; ++m)
    #pragma unroll
    for (int n = 0; n < 4; ++n){
      int col = wn * 64 + n * 16 + l15;
      #pragma unroll
      for (int r = 0; r < 4; ++r){
        int row = row0 + wm * 64 + m * 16 + lhi * 4 + r;
        if (row < M){
          C1[(size_t)row * 128 + col] = f2bf(acc[m][n][r]);
          C2[(size_t)row * 128 + col] = f2bf(acc2[m][n][r]);
        }
      }
    }
  // reduce dot partials over the 4 slot-lanes
  #pragma unroll
  for (int o = 1; o < 4; o <<= 1){
    dps0 += __shfl_xor(dps0, o); dpd0 += __shfl_xor(dpd0, o);
    dps1 += __shfl_xor(dps1, o); dpd1 += __shfl_xor(dpd1, o);
  }
  if (slot == 0){
    if (v0){ als[row0 + r0] = dps0;      ald[row0 + r0] = dpd0; }
    if (v1){ als[row0 + r0 + 64] = dps1; ald[row0 + r0 + 64] = dpd1; }
  }
}

// ---------------- layer-2 GEMM: bf16 A, dual B (Wsrc2, Wl2), bf16 C, reg-prefetch ----------------

__global__ __launch_bounds__(256) void gemm2_k(const short* __restrict__ A,
    const short* __restrict__ BT1, const short* __restrict__ BT2,
    short* __restrict__ C1, short* __restrict__ C2, int M){
  const int K = 128;
  __shared__ int4 As[512];
  __shared__ int4 Bs1[512];
  __shared__ int4 Bs2[512];
  const int tid = threadIdx.x;
  const int lane = tid & 63, wid = tid >> 6;
  const int wm = wid >> 1, wn = wid & 1;
  const int l15 = lane & 15, lhi = lane >> 4;
  const int row0 = blockIdx.x * 128;
  const int r0 = tid >> 2, slot = tid & 3;
  const int so0 = (slot * 16) ^ ((r0 & 3) << 4);

  const bool v0 = row0 + r0 < M, v1 = row0 + r0 + 64 < M;
  const short* A0 = A + (size_t)(row0 + r0) * K + slot * 8;
  const short* A1 = A0 + (size_t)64 * K;
  const short* B10 = BT1 + (size_t)r0 * K + slot * 8;
  const short* B11 = BT1 + (size_t)(r0 + 64) * K + slot * 8;
  const short* B20 = BT2 + (size_t)r0 * K + slot * 8;
  const short* B21 = BT2 + (size_t)(r0 + 64) * K + slot * 8;

  f32x4 acc[4][4], acc2[4][4];
  #pragma unroll
  for (int m = 0; m < 4; ++m)
    #pragma unroll
    for (int n = 0; n < 4; ++n){ acc[m][n] = (f32x4)(0.f); acc2[m][n] = (f32x4)(0.f); }

  int4 ra0, ra1, rb10, rb11, rb20, rb21;
  const int4 zi4 = make_int4(0, 0, 0, 0);

#define G2_LOAD(kk) do{ \
    ra0 = v0 ? *(const int4*)(A0 + (kk)) : zi4; \
    ra1 = v1 ? *(const int4*)(A1 + (kk)) : zi4; \
    rb10 = *(const int4*)(B10 + (kk)); rb11 = *(const int4*)(B11 + (kk)); \
    rb20 = *(const int4*)(B20 + (kk)); rb21 = *(const int4*)(B21 + (kk)); \
  }while(0)

  G2_LOAD(0);
  for (int kk = 0; kk < K; kk += 32){
    *(int4*)((char*)As + r0 * 64 + so0) = ra0;
    *(int4*)((char*)As + (r0 + 64) * 64 + so0) = ra1;
    *(int4*)((char*)Bs1 + r0 * 64 + so0) = rb10;
    *(int4*)((char*)Bs1 + (r0 + 64) * 64 + so0) = rb11;
    *(int4*)((char*)Bs2 + r0 * 64 + so0) = rb20;
    *(int4*)((char*)Bs2 + (r0 + 64) * 64 + so0) = rb21;
    __syncthreads();
    if (kk + 32 < K) G2_LOAD(kk + 32);
    bf16x8 af[4], bfr[4], bf2[4];
    #pragma unroll
    for (int m = 0; m < 4; ++m){
      int ar = wm * 64 + m * 16 + l15;
      af[m] = *(const bf16x8*)((const char*)As + ar * 64 + ((lhi * 16) ^ ((ar & 3) << 4)));
    }
    #pragma unroll
    for (int n = 0; n < 4; ++n){
      int bc = wn * 64 + n * 16 + l15;
      int so = (lhi * 16) ^ ((bc & 3) << 4);
      bfr[n] = *(const bf16x8*)((const char*)Bs1 + bc * 64 + so);
      bf2[n] = *(const bf16x8*)((const char*)Bs2 + bc * 64 + so);
    }
    #pragma unroll
    for (int m = 0; m < 4; ++m)
      #pragma unroll
      for (int n = 0; n < 4; ++n){
        acc[m][n]  = __builtin_amdgcn_mfma_f32_16x16x32_bf16(af[m], bfr[n], acc[m][n], 0, 0, 0);
        acc2[m][n] = __builtin_amdgcn_mfma_f32_16x16x32_bf16(af[m], bf2[n], acc2[m][n], 0, 0, 0);
      }
    __syncthreads();
  }
#undef G2_LOAD
  #pragma unroll
  for (int m = 0; m < 4; ++m)
    #pragma unroll
    for (int n = 0; n < 4; ++n){
      int col = wn * 64 + n * 16 + l15;
      #pragma unroll
      for (int r = 0; r < 4; ++r){
        int row = row0 + wm * 64 + m * 16 + lhi * 4 + r;
        if (row < M){
          C1[(size_t)row * 128 + col] = f2bf(acc[m][n][r]);
          C2[(size_t)row * 128 + col] = f2bf(acc2[m][n][r]);
        }
      }
    }
}

// ---------------- layer-1 aggregation: no-max softmax, 8-deep gather unroll, fused l2 dots ----------------

__global__ __launch_bounds__(256) void agg1_k(const int* __restrict__ rowptr, const int* __restrict__ csr,
    const short* __restrict__ hsrcb, const float* __restrict__ als, const float* __restrict__ ald,
    const short* __restrict__ linb, const float* __restrict__ bg, const float* __restrict__ bl,
    const float* __restrict__ ws2, const float* __restrict__ wd2,
    short* __restrict__ outb, float* __restrict__ als2, float* __restrict__ ald2, int N){
  int w = (blockIdx.x * blockDim.x + threadIdx.x) >> 6;
  int lane = threadIdx.x & 63;
  if (w >= N) return;
  int beg = rowptr[w], end = rowptr[w + 1];
  float aldi = ald[w];
  float denp = 0.f, a0 = 0.f, a1 = 0.f;
  int ch = lane << 1;
  for (int c = beg; c < end; c += 64){
    int j = c + lane;
    bool act = j < end;
    int s = act ? csr[j] : 0;
    float wt = 0.f;
    if (act){ float t = als[s] + aldi; t = (t > 0.f) ? t : 0.2f * t; wt = __expf(t); }
    denp += wt;
    int cnt = end - c; if (cnt > 64) cnt = 64;
    for (int q0 = 0; q0 < cnt; q0 += 8){
      float wq[8]; unsigned hp[8];
      #pragma unroll
      for (int u = 0; u < 8; ++u){
        int qq = q0 + u;
        int sq = __shfl(s, qq & 63);
        wq[u] = (qq < cnt) ? __shfl(wt, qq & 63) : 0.f;
        hp[u] = *(const unsigned*)(hsrcb + (size_t)sq * 128 + ch);
      }
      #pragma unroll
      for (int u = 0; u < 8; ++u){ a0 += wq[u] * bflo(hp[u]); a1 += wq[u] * bfhi(hp[u]); }
    }
  }
  float den = denp;
  #pragma unroll
  for (int o = 32; o; o >>= 1) den += __shfl_xor(den, o);
  float inv = (end > beg) ? 1.f / den : 0.f;
  unsigned lp = *(const unsigned*)(linb + (size_t)w * 128 + ch);
  float o0 = a0 * inv + bg[ch]     + bl[ch]     + bflo(lp);
  float o1 = a1 * inv + bg[ch + 1] + bl[ch + 1] + bfhi(lp);
  o0 = fmaxf(o0, 0.f); o1 = fmaxf(o1, 0.f);
  *(unsigned*)(outb + (size_t)w * 128 + ch) = pk2bf(o0, o1);
  float s2 = o0 * ws2[ch] + o1 * ws2[ch + 1];
  float d2 = o0 * wd2[ch] + o1 * wd2[ch + 1];
  #pragma unroll
  for (int o = 32; o; o >>= 1){ s2 += __shfl_xor(s2, o); d2 += __shfl_xor(d2, o); }
  if (lane == 0){ als2[w] = s2; ald2[w] = d2; }
}

// ---------------- fused tail: proj (fc3) + layer-2 aggregation (8 persons/block) + head ----------------

__global__ __launch_bounds__(512) void tail_k(
    const float* __restrict__ xp, const int* __restrict__ prjidx,
    const float* __restrict__ W3, const float* __restrict__ b3,
    const int* __restrict__ pidx,
    const int* __restrict__ rowptr, const int* __restrict__ csr,
    const short* __restrict__ h2, const float* __restrict__ als, const float* __restrict__ ald,
    const short* __restrict__ lin2all,
    const float* __restrict__ bg, const float* __restrict__ bl,
    const float* __restrict__ Wf1, const float* __restrict__ bf1,
    const float* __restrict__ Wf2, const float* __restrict__ bf2,
    float* __restrict__ outp, int Dp){
  __shared__ float xs[768];
  __shared__ float part[4][128];
  __shared__ float pe[8][128];
  __shared__ float pr[128];
  int b = blockIdx.x, t = threadIdx.x;
  // proj staging
  const float* xr = xp + (size_t)prjidx[b] * Dp;
  for (int i = t; i < Dp / 4; i += 512)
    ((float4*)xs)[i] = ((const float4*)xr)[i];
  __syncthreads();
  { int c = t & 127, h = t >> 7;
    float acc = 0.f;
    #pragma unroll 8
    for (int k = 0; k < 192; ++k)
      acc = fmaf(xs[h * 192 + k], W3[(size_t)(h * 192 + k) * 128 + c], acc);
    part[h][c] = acc; }
  // agg2: wave wv handles person b*8+wv
  int wv = t >> 6, lane = t & 63;
  int p = b * 8 + wv;
  int nd = pidx[p];
  int ch = lane << 1;
  int beg = rowptr[nd], end = rowptr[nd + 1];
  float aldi = ald[nd];
  float denp = 0.f, a0 = 0.f, a1 = 0.f;
  for (int c = beg; c < end; c += 64){
    int j = c + lane;
    bool act = j < end;
    int s = act ? csr[j] : 0;
    float wt = 0.f;
    if (act){ float tt = als[s] + aldi; tt = (tt > 0.f) ? tt : 0.2f * tt; wt = __expf(tt); }
    denp += wt;
    int cnt = end - c; if (cnt > 64) cnt = 64;
    for (int q0 = 0; q0 < cnt; q0 += 8){
      float wq[8]; unsigned hp[8];
      #pragma unroll
      for (int u = 0; u < 8; ++u){
        int qq = q0 + u;
        int sq = __shfl(s, qq & 63);
        wq[u] = (qq < cnt) ? __shfl(wt, qq & 63) : 0.f;
        hp[u] = *(const unsigned*)(h2 + (size_t)sq * 128 + ch);
      }
      #pragma unroll
      for (int u = 0; u < 8; ++u){ a0 += wq[u] * bflo(hp[u]); a1 += wq[u] * bfhi(hp[u]); }
    }
  }
  float den = denp;
  #pragma unroll
  for (int o = 32; o; o >>= 1) den += __shfl_xor(den, o);
  float inv = (end > beg) ? 1.f / den : 0.f;
  unsigned lp = *(const unsigned*)(lin2all + (size_t)nd * 128 + ch);
  pe[wv][ch]     = a0 * inv + bg[ch]     + bl[ch]     + bflo(lp);
  pe[wv][ch + 1] = a1 * inv + bg[ch + 1] + bl[ch + 1] + bfhi(lp);
  __syncthreads();
  if (t < 128) pr[t] = part[0][t] + part[1][t] + part[2][t] + part[3][t] + b3[t];
  __syncthreads();
  // head: wave wv -> person wv; lane covers cols lane, lane+64
  float v = 0.f;
  for (int cc = lane; cc < 128; cc += 64){
    float acc = bf1[cc];
    for (int k = 0; k < 128; ++k)
      acc += pe[wv][k] * Wf1[(size_t)k * 128 + cc] + pr[k] * Wf1[(size_t)(128 + k) * 128 + cc];
    v += fmaxf(acc, 0.f) * Wf2[cc];
  }
  #pragma unroll
  for (int o = 32; o; o >>= 1) v += __shfl_xor(v, o);
  if (lane == 0) outp[(size_t)b * 8 + wv] = v + bf2[0];
}

// ---------------- launch ----------------

extern "C" void kernel_launch(void* const* d_in, const int* in_sizes, int n_in,
                              void* d_out, int out_size, void* d_ws, size_t ws_size,
                              hipStream_t stream){
  const float* x      = (const float*)d_in[0];
  const int*   eidx   = (const int*)d_in[1];
  const float* xproj  = (const float*)d_in[2];
  const int*   pidx   = (const int*)d_in[3];
  const int*   prjidx = (const int*)d_in[4];
  const float* Wsrc1  = (const float*)d_in[5];
  const float* Wdst1  = (const float*)d_in[6];
  const float* asrc1  = (const float*)d_in[7];
  const float* adst1  = (const float*)d_in[8];
  const float* b1     = (const float*)d_in[9];
  const float* Wl1    = (const float*)d_in[10];
  const float* bl1    = (const float*)d_in[11];
  const float* Wsrc2  = (const float*)d_in[12];
  const float* Wdst2  = (const float*)d_in[13];
  const float* asrc2  = (const float*)d_in[14];
  const float* adst2  = (const float*)d_in[15];
  const float* b2     = (const float*)d_in[16];
  const float* Wl2    = (const float*)d_in[17];
  const float* bl2    = (const float*)d_in[18];
  const float* W3     = (const float*)d_in[19];
  const float* b3     = (const float*)d_in[20];
  const float* Wf1    = (const float*)d_in[21];
  const float* bf1    = (const float*)d_in[22];
  const float* Wf2    = (const float*)d_in[23];
  const float* bf2    = (const float*)d_in[24];

  const int DIN = 256, H = 128, DPROJ = 768;
  const int N  = in_sizes[0] / DIN;
  const int E  = in_sizes[1] / 2;
  const int P  = in_sizes[3];            // B*K = 2048
  const int B  = in_sizes[4];            // 256
  const int* srcv = eidx;
  const int* dstv = eidx + E;
  const int NB = cdiv(N, 1024);
  (void)H; (void)P;

  char* ws = (char*)d_ws;
  size_t off = 0;
  auto alloc = [&](size_t bytes) -> void* {
    void* p = ws + off;
    off = (off + bytes + 255) & ~(size_t)255;
    return p;
  };
  short* hbuf   = (short*)alloc((size_t)N * 128 * 2);   // bf16 h_src1, later h_src2
  short* linb   = (short*)alloc((size_t)N * 128 * 2);   // bf16 x@Wl1, later x1@Wl2
  short* x1b    = (short*)alloc((size_t)N * 128 * 2);   // bf16 x1
  float* als1   = (float*)alloc((size_t)N * 4);
  float* ald1   = (float*)alloc((size_t)N * 4);
  float* als2   = (float*)alloc((size_t)N * 4);
  float* ald2   = (float*)alloc((size_t)N * 4);
  float* wa_s1  = (float*)alloc(256 * 4);
  float* wa_d1  = (float*)alloc(256 * 4);
  float* wa_s2  = (float*)alloc(128 * 4);
  float* wa_d2  = (float*)alloc(128 * 4);
  short* WsT1   = (short*)alloc((size_t)128 * 256 * 2);
  short* WlT1   = (short*)alloc((size_t)128 * 256 * 2);
  short* WsT2   = (short*)alloc((size_t)128 * 128 * 2);
  short* WlT2   = (short*)alloc((size_t)128 * 128 * 2);
  int*   deg    = (int*)alloc((size_t)N * 4);
  int*   rowptr = (int*)alloc((size_t)(N + 1) * 4);
  int*   cursor = (int*)alloc((size_t)N * 4);
  int*   bsum   = (int*)alloc((size_t)1024 * 4);
  int*   csr    = (int*)alloc((size_t)E * 4);
  (void)ws_size; (void)n_in; (void)out_size;

  // CSR build
  zero_i32_k<<<cdiv(N, 1024), 1024, 0, stream>>>(deg, N);
  deg_count_k<<<cdiv(E, 256), 256, 0, stream>>>(dstv, E, deg);
  scan1_k<<<NB, 1024, 0, stream>>>(deg, N, rowptr, bsum);
  scan2_k<<<1, 1024, 0, stream>>>(bsum, NB, rowptr + N);
  scan3_k<<<NB, 1024, 0, stream>>>(rowptr, cursor, bsum, N);
  scatter_k<<<cdiv(E, 256), 256, 0, stream>>>(srcv, dstv, E, cursor, csr);

  // weight prep (transposes + combined attention vectors)
  prepc_k<<<515, 256, 0, stream>>>(Wsrc1, WsT1, Wl1, WlT1, Wsrc2, WsT2, Wl2, WlT2,
                                   asrc1, Wdst1, adst1, asrc2, Wdst2, adst2,
                                   wa_s1, wa_d1, wa_s2, wa_d2);

  // layer 1: h1 = x@Wsrc1, lin1 = x@Wl1, als1/ald1 fused (fp32 dots)
  gemm1_k<<<cdiv(N, 128), 256, 0, stream>>>(x, WsT1, WlT1, wa_s1, wa_d1,
                                            hbuf, linb, als1, ald1, N);
  agg1_k<<<cdiv(N, 4), 256, 0, stream>>>(rowptr, csr, hbuf, als1, ald1, linb, b1, bl1,
                                         wa_s2, wa_d2, x1b, als2, ald2, N);

  // layer 2: h2 = x1@Wsrc2, lin2all = x1@Wl2 (dual)
  gemm2_k<<<cdiv(N, 128), 256, 0, stream>>>(x1b, WsT2, WlT2, hbuf, linb, N);

  // fused proj + agg2 + head
  tail_k<<<B, 512, 0, stream>>>(xproj, prjidx, W3, b3, pidx, rowptr, csr,
                                hbuf, als2, ald2, linb, b2, bl2,
                                Wf1, bf1, Wf2, bf2, (float*)d_out, DPROJ);
}